// Round 16
// baseline (114.013 us; speedup 1.0000x reference)
//
#include <hip/hip_runtime.h>
#include <hip/hip_bf16.h>

namespace {

constexpr int kS = 4097;      // sequence incl. CLS
constexpr int kL = 4096;      // patch tokens
constexpr int kE = 768;
constexpr int kH = 12;
constexpr int kD = 64;
constexpr int kQKVN = 2304;
constexpr int kT = 1024;      // lattice length per residue (kL / kDil)
constexpr int kClsChunks = 32;
constexpr int kClsStride = 68;    // 64 acc + m + l, padded
constexpr float kScale = 0.125f;  // 1/sqrt(64)

typedef short short8 __attribute__((ext_vector_type(8)));
typedef short short4v __attribute__((ext_vector_type(4)));
typedef float f32x4 __attribute__((ext_vector_type(4)));

__device__ inline short f2bf(float x) {
  __hip_bfloat16 b = __float2bfloat16(x);
  return *reinterpret_cast<short*>(&b);
}
__device__ inline float bf2f(short u) {
  unsigned int x = ((unsigned int)(unsigned short)u) << 16;
  union { unsigned int u32; float f; } c;
  c.u32 = x;
  return c.f;
}

__device__ inline void store_c(float* p, float v) { *p = v; }
__device__ inline void store_c(short* p, float v) { *p = f2bf(v); }

// m204 bijective XCD swizzle: consecutive output ids share an XCD.
__device__ inline int xcd_swz(int bid, int nwg) {
  const int q = nwg >> 3, r = nwg & 7;
  const int x = bid & 7, o = bid >> 3;
  return (x < r ? x * (q + 1) : r * (q + 1) + (x - r) * q) + o;
}

#define GLOAD_LDS16(g, l)                                                        \
  __builtin_amdgcn_global_load_lds(                                              \
      (const __attribute__((address_space(1))) unsigned int*)(g),                \
      (__attribute__((address_space(3))) unsigned int*)(l), 16, 0, 0)

// Fused fp32->bf16 convert of x, qkv_w, out_w in one grid-stride kernel.
__global__ __launch_bounds__(256) void cvt3_kernel(const float* __restrict__ x,
                                                   const float* __restrict__ w,
                                                   const float* __restrict__ ow,
                                                   short* __restrict__ xb,
                                                   short* __restrict__ wb,
                                                   short* __restrict__ owb,
                                                   int n4x, int n4w, int n4o) {
  const int total = n4x + n4w + n4o;
  int i = blockIdx.x * blockDim.x + threadIdx.x;
  const int stride = gridDim.x * blockDim.x;
  for (; i < total; i += stride) {
    const float* src;
    short* dst;
    int k;
    if (i < n4x) { src = x; dst = xb; k = i; }
    else if (i < n4x + n4w) { src = w; dst = wb; k = i - n4x; }
    else { src = ow; dst = owb; k = i - n4x - n4w; }
    f32x4 v = reinterpret_cast<const f32x4*>(src)[k];
    short4v o;
#pragma unroll
    for (int j = 0; j < 4; ++j) o[j] = f2bf(v[j]);
    reinterpret_cast<short4v*>(dst)[k] = o;
  }
}

// ============================================================================
// 8-phase 256x256 GEMM (m201-template port). C[M][N] = A*W^T + bias, K=768.
// 512 threads = 8 waves (2m x 4n); per wave 128x64 output (8x4 16x16 frags).
// LDS: [2 dbuf][2 half][128][64] bf16 per operand = 128 KB. BK=64, 12 K-tiles,
// 6 iterations x 8 phases. Per phase: {ds_read subtile -> regs; stage 1
// half-tile (2 gload_lds, pre-swizzled source chunk^(row&7), linear LDS dest);
// barrier; lgkmcnt(0); setprio(1) 16 MFMA setprio(0); barrier}.
// Stage->phase mapping chosen so each staged region's last reader finished a
// PRIOR phase (2 barriers/phase make that chip-wide): ph0/1: A(kt1)->buf1;
// ph2/3: B(kt0+2)->buf0; ph4/5: A(kt0+2)->buf0; ph6/7: B(kt1+2)->buf1.
// Counted vmcnt(4) at ph3/ph7 boundaries retires exactly the halves the next
// K-tile reads (unit accounting: prologue 12 units, 2/phase, verified).
// ROPE: 2D rope + q-scale fused into the epilogue (QKV GEMM).
// ============================================================================
template <bool ROPE, typename TC>
__global__ __launch_bounds__(512, 2) void gemm_8ph_kernel(const short* __restrict__ A,
                                                          const short* __restrict__ W,
                                                          const float* __restrict__ bias,
                                                          TC* __restrict__ C,
                                                          int Mreal, int N, int K, int ntm,
                                                          const int* __restrict__ coords) {
  __shared__ short Ash[2][2][128 * 64];  // 64 KB
  __shared__ short Bsh[2][2][128 * 64];  // 64 KB
  const int nwg = gridDim.x;
  const int wid = xcd_swz(blockIdx.x, nwg);
  const int m0 = (wid % ntm) * 256;
  const int n0 = (wid / ntm) * 256;
  const int t = threadIdx.x;  // 0..511
  const int lane = t & 63;
  const int wave = t >> 6;    // 0..7
  const int wm = wave >> 2;   // 0..1 (A half owned)
  const int wn = wave & 3;    // 0..3
  const int lrow = lane & 15;
  const int lgrp = lane >> 4;

  // Staging map: thread t covers chunks c = j*512+t (j=0,1) of a 128x64 half
  // (8 16B-chunks/row). LDS dest linear (c*16B); global source chunk XOR'd.
  int srow[2], scol[2];
#pragma unroll
  for (int j = 0; j < 2; ++j) {
    const int c = j * 512 + t;
    srow[j] = c >> 3;
    scol[j] = ((c & 7) ^ (srow[j] & 7)) << 3;
  }

#define STAGEA(kt, h)                                                         \
  do {                                                                        \
    _Pragma("unroll") for (int j = 0; j < 2; ++j) {                           \
      int gr = m0 + (h) * 128 + srow[j];                                      \
      if (gr > Mreal - 1) gr = Mreal - 1;                                     \
      GLOAD_LDS16(A + (size_t)gr * K + (kt) * 64 + scol[j],                   \
                  &Ash[(kt) & 1][h][(j * 512 + t) * 8]);                      \
    }                                                                         \
  } while (0)
#define STAGEB(kt, h)                                                         \
  do {                                                                        \
    _Pragma("unroll") for (int j = 0; j < 2; ++j) {                           \
      const int gr = n0 + (h) * 128 + srow[j];                                \
      GLOAD_LDS16(W + (size_t)gr * K + (kt) * 64 + scol[j],                   \
                  &Bsh[(kt) & 1][h][(j * 512 + t) * 8]);                      \
    }                                                                         \
  } while (0)

  short8 breg[4][2], areg[2][2];
#define READB(buf)                                                            \
  do {                                                                        \
    _Pragma("unroll") for (int nf = 0; nf < 4; ++nf)                          \
      _Pragma("unroll") for (int ks = 0; ks < 2; ++ks) {                      \
        const int rowh = (wn & 1) * 64 + nf * 16 + lrow;                      \
        const int ch = (ks * 4 + lgrp) ^ (rowh & 7);                          \
        breg[nf][ks] = *reinterpret_cast<const short8*>(                      \
            &Bsh[buf][wn >> 1][rowh * 64 + ch * 8]);                          \
      }                                                                       \
  } while (0)
#define READA(buf, p)                                                         \
  do {                                                                        \
    _Pragma("unroll") for (int mi = 0; mi < 2; ++mi)                          \
      _Pragma("unroll") for (int ks = 0; ks < 2; ++ks) {                      \
        const int rowh = ((p) * 2 + mi) * 16 + lrow;                          \
        const int ch = (ks * 4 + lgrp) ^ (rowh & 7);                          \
        areg[mi][ks] = *reinterpret_cast<const short8*>(                      \
            &Ash[buf][wm][rowh * 64 + ch * 8]);                               \
      }                                                                       \
  } while (0)
#define MFMA16(p)                                                             \
  do {                                                                        \
    _Pragma("unroll") for (int mi = 0; mi < 2; ++mi)                          \
      _Pragma("unroll") for (int nf = 0; nf < 4; ++nf)                        \
        _Pragma("unroll") for (int ks = 0; ks < 2; ++ks)                      \
          acc[(p) * 2 + mi][nf] = __builtin_amdgcn_mfma_f32_16x16x32_bf16(    \
              areg[mi][ks], breg[nf][ks], acc[(p) * 2 + mi][nf], 0, 0, 0);    \
  } while (0)
#define WAIT_LGKM0                                                            \
  do {                                                                        \
    asm volatile("s_waitcnt lgkmcnt(0)" ::: "memory");                        \
    __builtin_amdgcn_sched_barrier(0);                                        \
  } while (0)
#define BAR                                                                   \
  do {                                                                        \
    __builtin_amdgcn_sched_barrier(0);                                        \
    __builtin_amdgcn_s_barrier();                                             \
    __builtin_amdgcn_sched_barrier(0);                                        \
  } while (0)
#define PHASE(buf, p, STAGE_STMT)                                             \
  do {                                                                        \
    READA(buf, p);                                                            \
    STAGE_STMT;                                                               \
    BAR;                                                                      \
    WAIT_LGKM0;                                                               \
    __builtin_amdgcn_s_setprio(1);                                            \
    MFMA16(p);                                                                \
    __builtin_amdgcn_s_setprio(0);                                            \
  } while (0)

  f32x4 acc[8][4] = {};

  // Prologue: kt0=0 (all 4 halves -> buf0) + B of kt1=1 (-> buf1) = 12 units.
  STAGEA(0, 0); STAGEA(0, 1); STAGEB(0, 0); STAGEB(0, 1);
  STAGEB(1, 0); STAGEB(1, 1);
  asm volatile("s_waitcnt vmcnt(4)" ::: "memory");  // kt0 resident; B(kt1) in flight
  BAR;

  for (int it = 0; it < 6; ++it) {
    const int kt1 = 2 * it + 1;
    const int ktA = 2 * it + 2;  // next even K-tile (buf0)
    const int ktB = 2 * it + 3;  // next odd K-tile (buf1)
    const bool more = (it < 5);

    // ===== K-tile kt0 = 2*it (buf0) =====
    READB(0);
    PHASE(0, 0, STAGEA(kt1, 0));  // A0(kt1)->buf1: buf1-A last read prev iter ph7
    BAR;
    PHASE(0, 1, STAGEA(kt1, 1));
    BAR;
    PHASE(0, 2, if (more) STAGEB(ktA, 0));  // buf0-B last read this iter ph0
    BAR;
    PHASE(0, 3, if (more) STAGEB(ktA, 1));
    if (more) { asm volatile("s_waitcnt vmcnt(4)" ::: "memory"); }
    else      { asm volatile("s_waitcnt vmcnt(0)" ::: "memory"); }  // A(kt1) resident
    BAR;

    // ===== K-tile kt1 = 2*it+1 (buf1) =====
    READB(1);
    PHASE(1, 0, if (more) STAGEA(ktA, 0));  // buf0-A last read this iter ph3
    BAR;
    PHASE(1, 1, if (more) STAGEA(ktA, 1));
    BAR;
    PHASE(1, 2, if (more) STAGEB(ktB, 0));  // buf1-B last read this iter ph4
    BAR;
    PHASE(1, 3, if (more) STAGEB(ktB, 1));
    if (more) { asm volatile("s_waitcnt vmcnt(4)" ::: "memory"); }  // kt0+2 resident
    BAR;
  }
#undef STAGEA
#undef STAGEB
#undef READB
#undef READA
#undef MFMA16
#undef WAIT_LGKM0
#undef BAR
#undef PHASE

  // Epilogue. C/D layout (m89): col = lane&15, row = (lane>>4)*4 + reg.
  const int rg = lgrp << 2;
#pragma unroll
  for (int nf = 0; nf < 4; ++nf) {
    const int col = n0 + wn * 64 + nf * 16 + lrow;
    const float bz = bias[col];
    const int sec = col / 768;  // 0=q 1=k 2=v; uniform per nf (768%16==0)
    const int dh = col & 63;
    const bool odd = dh & 1;
    const int jf = (dh >> 1) & 15;
    const bool usex = (dh >> 1) < 16;
    const float invf = __powf(10000.0f, -(float)jf * (1.0f / 16.0f));
#pragma unroll
    for (int mf = 0; mf < 8; ++mf) {
      const int rowb = m0 + wm * 128 + mf * 16 + rg;
#pragma unroll
      for (int r = 0; r < 4; ++r) {
        const int row = rowb + r;
        float v = acc[mf][nf][r] + bz;
        if (ROPE && sec != 2) {
          const float partner = __shfl_xor(v, 1);  // pair element (w/ its bias)
          float cs = 1.f, sn = 0.f;
          if (row > 0) {  // uniform within 16-lane group
            const int cl = min(row, kS - 1) - 1;
            const float cx = (float)coords[cl * 2] * 1e-5f;
            const float cy = (float)coords[cl * 2 + 1] * 1e-5f;
            __sincosf((usex ? cx : cy) * invf, &sn, &cs);
          }
          v = odd ? (v * cs + partner * sn) : (v * cs - partner * sn);
          if (sec == 0) v *= kScale;  // q pre-scaled (incl CLS row)
        }
        if (row < Mreal) store_c(&C[(size_t)row * N + col], v);
      }
    }
  }
}

// r13 BK=64 swizzled 2-phase GEMM (proven 95.7us config) — used for gemm2.
template <bool ROPE, typename TC>
__global__ __launch_bounds__(256) void gemm_tile_kernel(const short* __restrict__ A,
                                                        const short* __restrict__ W,
                                                        const float* __restrict__ bias,
                                                        TC* __restrict__ C,
                                                        int Mreal, int N, int K, int ntm,
                                                        const int* __restrict__ coords) {
  __shared__ short Ash[2][64 * 64];
  __shared__ short Bsh[2][128 * 64];
  const int nwg = gridDim.x;
  const int wid = xcd_swz(blockIdx.x, nwg);
  const int m0 = (wid % ntm) * 64;
  const int n0 = (wid / ntm) * 128;
  const int t = threadIdx.x;
  const int lane = t & 63;
  const int wave = t >> 6;
  const int wr = wave >> 1, wc = wave & 1;
  const int lrow = lane & 15;
  const int lgrp = lane >> 4;

  const int srow = t >> 3;
  const int scol = ((t & 7) ^ (srow & 7)) << 3;
  int ar0 = m0 + srow;       if (ar0 > Mreal - 1) ar0 = Mreal - 1;
  int ar1 = m0 + 32 + srow;  if (ar1 > Mreal - 1) ar1 = Mreal - 1;
  const int br0 = n0 + srow, br1 = n0 + 32 + srow;
  const int br2 = n0 + 64 + srow, br3 = n0 + 96 + srow;

#define STAGE(buf, k0)                                                  \
  do {                                                                  \
    GLOAD_LDS16(A + (size_t)ar0 * K + (k0) + scol, &Ash[buf][t * 8]);   \
    GLOAD_LDS16(A + (size_t)ar1 * K + (k0) + scol, &Ash[buf][2048 + t * 8]); \
    GLOAD_LDS16(W + (size_t)br0 * K + (k0) + scol, &Bsh[buf][t * 8]);   \
    GLOAD_LDS16(W + (size_t)br1 * K + (k0) + scol, &Bsh[buf][2048 + t * 8]); \
    GLOAD_LDS16(W + (size_t)br2 * K + (k0) + scol, &Bsh[buf][4096 + t * 8]); \
    GLOAD_LDS16(W + (size_t)br3 * K + (k0) + scol, &Bsh[buf][6144 + t * 8]); \
  } while (0)

  f32x4 acc[2][4] = {};
  const int nsteps = K / 64;

  STAGE(0, 0);
  __syncthreads();

  int cur = 0;
  for (int tt = 0; tt < nsteps; ++tt) {
    if (tt + 1 < nsteps) STAGE(cur ^ 1, (tt + 1) * 64);

#pragma unroll
    for (int ks = 0; ks < 2; ++ks) {
      short8 a[2], b[4];
#pragma unroll
      for (int mi = 0; mi < 2; ++mi) {
        const int row = wr * 32 + mi * 16 + lrow;
        const int ch = (ks * 4 + lgrp) ^ (row & 7);
        a[mi] = *reinterpret_cast<const short8*>(&Ash[cur][row * 64 + ch * 8]);
      }
#pragma unroll
      for (int ni = 0; ni < 4; ++ni) {
        const int row = wc * 64 + ni * 16 + lrow;
        const int ch = (ks * 4 + lgrp) ^ (row & 7);
        b[ni] = *reinterpret_cast<const short8*>(&Bsh[cur][row * 64 + ch * 8]);
      }
#pragma unroll
      for (int mi = 0; mi < 2; ++mi)
#pragma unroll
        for (int ni = 0; ni < 4; ++ni)
          acc[mi][ni] = __builtin_amdgcn_mfma_f32_16x16x32_bf16(a[mi], b[ni], acc[mi][ni], 0, 0, 0);
    }

    __syncthreads();
    cur ^= 1;
  }
#undef STAGE

  const int rg = lgrp << 2;
  for (int ni = 0; ni < 4; ++ni) {
    const int col = n0 + wc * 64 + ni * 16 + lrow;
    const float bz = bias[col];
    const int sec = col / 768;
    const int dh = col & 63;
    const bool odd = dh & 1;
    const int jf = (dh >> 1) & 15;
    const bool usex = (dh >> 1) < 16;
    const float invf = __powf(10000.0f, -(float)jf * (1.0f / 16.0f));
    for (int mi = 0; mi < 2; ++mi) {
      const int rowb = m0 + wr * 32 + mi * 16 + rg;
#pragma unroll
      for (int r = 0; r < 4; ++r) {
        const int row = rowb + r;
        float v = acc[mi][ni][r] + bz;
        if (ROPE && sec != 2) {
          const float partner = __shfl_xor(v, 1);
          float cs = 1.f, sn = 0.f;
          if (row > 0) {
            const int cl = min(row, kS - 1) - 1;
            const float cx = (float)coords[cl * 2] * 1e-5f;
            const float cy = (float)coords[cl * 2 + 1] * 1e-5f;
            __sincosf((usex ? cx : cy) * invf, &sn, &cs);
          }
          v = odd ? (v * cs + partner * sn) : (v * cs - partner * sn);
          if (sec == 0) v *= kScale;
        }
        if (row < Mreal) store_c(&C[(size_t)row * N + col], v);
      }
    }
  }
}

// Fused attention kernel:
//  blocks [0,384):   MFMA patch attention (lattice coords), 4 waves = 4 units
//  blocks [384,768): CLS split-K partials (h = idx>>5, chunk = idx&31)
__global__ __launch_bounds__(256) void attn_kernel(const short* __restrict__ qkv,
                                                   short* __restrict__ attn,
                                                   float* __restrict__ part) {
  __shared__ short Pl[4][32][104];
  __shared__ float sm[4], sl[4], sa[4][64];
  const int lane = threadIdx.x & 63;
  const int wv = threadIdx.x >> 6;

  if (blockIdx.x >= 384) {  // ---------- CLS partial ----------
    const int idx = blockIdx.x - 384;
    const int h = idx >> 5;
    const int c = idx & 31;
    const int start = c * 128;
    const int end = (c == kClsChunks - 1) ? kS : start + 128;
    const float qd = bf2f(qkv[h * kD + lane]);  // scaled q, row 0
    float m = -INFINITY, lsum = 0.f, acc = 0.f;
    for (int s = start + wv; s < end; s += 4) {
      float tt = qd * bf2f(qkv[(size_t)s * kQKVN + kE + h * kD + lane]);
      tt += __shfl_xor(tt, 1); tt += __shfl_xor(tt, 2); tt += __shfl_xor(tt, 4);
      tt += __shfl_xor(tt, 8); tt += __shfl_xor(tt, 16); tt += __shfl_xor(tt, 32);
      const float vd = bf2f(qkv[(size_t)s * kQKVN + 2 * kE + h * kD + lane]);
      const float mnew = fmaxf(m, tt);
      const float cor = __expf(m - mnew);
      const float p = __expf(tt - mnew);
      lsum = lsum * cor + p;
      acc = acc * cor + p * vd;
      m = mnew;
    }
    sa[wv][lane] = acc;
    if (lane == 0) { sm[wv] = m; sl[wv] = lsum; }
    __syncthreads();
    if (wv == 0) {
      float M = fmaxf(fmaxf(sm[0], sm[1]), fmaxf(sm[2], sm[3]));
      float Lt = 0.f, Av = 0.f;
#pragma unroll
      for (int w = 0; w < 4; ++w) {
        const float cw = __expf(sm[w] - M);
        Lt += sl[w] * cw;
        Av += sa[w][lane] * cw;
      }
      float* p = part + ((size_t)h * kClsChunks + c) * kClsStride;
      p[lane] = Av;
      if (lane == 0) { p[64] = M; p[65] = Lt; }
    }
    return;
  }

  // ---------- patch attention ----------
  const int unit = blockIdx.x * 4 + wv;
  const int t0 = (unit & 31) * 32;
  const int res = (unit >> 5) & 3;
  const int h = unit >> 7;
  const int lrow = lane & 15;
  const int lgrp = lane >> 4;
  const int kg = lgrp * 8;
  const int rg = lgrp * 4;

  // ---- QK^T ----
  f32x4 s_acc[2][4] = {};
  f32x4 s_cls[2] = {};
  short8 aq[2][2];
#pragma unroll
  for (int mi = 0; mi < 2; ++mi) {
    const int tq = t0 + mi * 16 + lrow;
    const size_t row = (size_t)(4 * tq + res + 1) * kQKVN + h * kD;
#pragma unroll
    for (int ks = 0; ks < 2; ++ks)
      aq[mi][ks] = *reinterpret_cast<const short8*>(qkv + row + ks * 32 + kg);
  }
#pragma unroll
  for (int ni = 0; ni < 4; ++ni) {
    int u = t0 - 16 + ni * 16 + lrow;
    u = min(max(u, 0), kT - 1);  // clamp; invalid cols masked in softmax
    const size_t row = (size_t)(4 * u + res + 1) * kQKVN + kE + h * kD;
    short8 bk[2];
#pragma unroll
    for (int ks = 0; ks < 2; ++ks)
      bk[ks] = *reinterpret_cast<const short8*>(qkv + row + ks * 32 + kg);
#pragma unroll
    for (int mi = 0; mi < 2; ++mi)
#pragma unroll
      for (int ks = 0; ks < 2; ++ks)
        s_acc[mi][ni] = __builtin_amdgcn_mfma_f32_16x16x32_bf16(aq[mi][ks], bk[ks], s_acc[mi][ni], 0, 0, 0);
  }
  {  // CLS key column
    short8 bc[2] = {};
    if (lrow == 0) {
#pragma unroll
      for (int ks = 0; ks < 2; ++ks)
        bc[ks] = *reinterpret_cast<const short8*>(qkv + kE + h * kD + ks * 32 + kg);
    }
#pragma unroll
    for (int mi = 0; mi < 2; ++mi)
#pragma unroll
      for (int ks = 0; ks < 2; ++ks)
        s_cls[mi] = __builtin_amdgcn_mfma_f32_16x16x32_bf16(aq[mi][ks], bc[ks], s_cls[mi], 0, 0, 0);
  }

  // ---- zero-fill P cols 64..95 ----
#pragma unroll
  for (int i = 0; i < 2; ++i) {
    const int idx = i * 64 + lane;
    const int q = idx >> 2, ch = idx & 3;
    short8 z = {};
    *reinterpret_cast<short8*>(&Pl[wv][q][64 + ch * 8]) = z;
  }

  // ---- softmax per query row (C-layout), write normalized P ----
#pragma unroll
  for (int mi = 0; mi < 2; ++mi) {
#pragma unroll
    for (int r = 0; r < 4; ++r) {
      const int q = mi * 16 + rg + r;
      float sw[4];
      float m = -INFINITY;
#pragma unroll
      for (int ni = 0; ni < 4; ++ni) {
        const int kk = ni * 16 + lrow;
        const int u = t0 - 16 + kk;
        const bool valid = (kk >= q) & (kk <= q + 32) & (u >= 0) & (u < kT);
        sw[ni] = valid ? s_acc[mi][ni][r] : -INFINITY;
        m = fmaxf(m, sw[ni]);
      }
      float scl = (lrow == 0) ? s_cls[mi][r] : -INFINITY;
      m = fmaxf(m, scl);
      m = fmaxf(m, __shfl_xor(m, 1)); m = fmaxf(m, __shfl_xor(m, 2));
      m = fmaxf(m, __shfl_xor(m, 4)); m = fmaxf(m, __shfl_xor(m, 8));
      float lsum = 0.f, ps[4];
#pragma unroll
      for (int ni = 0; ni < 4; ++ni) { ps[ni] = __expf(sw[ni] - m); lsum += ps[ni]; }
      const float pc = __expf(scl - m);
      lsum += pc;
      lsum += __shfl_xor(lsum, 1); lsum += __shfl_xor(lsum, 2);
      lsum += __shfl_xor(lsum, 4); lsum += __shfl_xor(lsum, 8);
      const float inv = __builtin_amdgcn_rcpf(lsum);
#pragma unroll
      for (int ni = 0; ni < 4; ++ni) Pl[wv][q][ni * 16 + lrow] = f2bf(ps[ni] * inv);
      if (lrow == 0) Pl[wv][q][64] = f2bf(pc * inv);
    }
  }

  // ---- PV: out[d][q] += V^T[d][kk] * P[q][kk] ----
  f32x4 o_acc[4][2] = {};
#pragma unroll
  for (int ks = 0; ks < 3; ++ks) {
    short8 bp[2];
#pragma unroll
    for (int nq = 0; nq < 2; ++nq)
      bp[nq] = *reinterpret_cast<const short8*>(&Pl[wv][nq * 16 + lrow][ks * 32 + kg]);
    short8 av[4];
#pragma unroll
    for (int md = 0; md < 4; ++md) {
      if (ks < 2) {
        const int d = md * 16 + lrow;
#pragma unroll
        for (int e = 0; e < 8; ++e) {
          const int kk = ks * 32 + kg + e;
          int u = t0 - 16 + kk;
          u = min(max(u, 0), kT - 1);  // invalid kk have P==0
          av[md][e] = qkv[(size_t)(4 * u + res + 1) * kQKVN + 2 * kE + h * kD + d];
        }
      } else {
        short8 z = {};
        av[md] = z;
        if (lgrp == 0)  // kk==64 -> v_cls
          av[md][0] = qkv[2 * kE + h * kD + md * 16 + lrow];
      }
#pragma unroll
      for (int nq = 0; nq < 2; ++nq)
        o_acc[md][nq] = __builtin_amdgcn_mfma_f32_16x16x32_bf16(av[md], bp[nq], o_acc[md][nq], 0, 0, 0);
    }
  }

  // ---- store ----
#pragma unroll
  for (int md = 0; md < 4; ++md)
#pragma unroll
    for (int nq = 0; nq < 2; ++nq)
#pragma unroll
      for (int r = 0; r < 4; ++r) {
        const int d = md * 16 + rg + r;
        const int q = nq * 16 + lrow;
        const int s = 4 * (t0 + q) + res + 1;
        attn[(size_t)s * kE + h * kD + d] = f2bf(o_acc[md][nq][r]);
      }
}

// CLS attention pass 2: combine 32 partials per head. 12 blocks x 64 lanes.
__global__ __launch_bounds__(64) void cls_combine_kernel(const float* __restrict__ part,
                                                         short* __restrict__ attn) {
  const int h = blockIdx.x;
  const int lane = threadIdx.x;
  float mc[kClsChunks], lc[kClsChunks], ac[kClsChunks];
#pragma unroll
  for (int c = 0; c < kClsChunks; ++c) {
    const float* p = part + ((size_t)h * kClsChunks + c) * kClsStride;
    mc[c] = p[64];
    lc[c] = p[65];
    ac[c] = p[lane];
  }
  float M = -INFINITY;
#pragma unroll
  for (int c = 0; c < kClsChunks; ++c) M = fmaxf(M, mc[c]);
  float L = 0.f, A = 0.f;
#pragma unroll
  for (int c = 0; c < kClsChunks; ++c) {
    const float w = __expf(mc[c] - M);
    L += lc[c] * w;
    A += ac[c] * w;
  }
  attn[h * kD + lane] = f2bf(A / L);
}

}  // namespace

extern "C" void kernel_launch(void* const* d_in, const int* in_sizes, int n_in,
                              void* d_out, int out_size, void* d_ws, size_t ws_size,
                              hipStream_t stream) {
  const float* x = (const float*)d_in[0];
  const int* coords = (const int*)d_in[1];
  const float* qkv_w = (const float*)d_in[2];
  const float* qkv_b = (const float*)d_in[3];
  const float* out_w = (const float*)d_in[4];
  const float* out_b = (const float*)d_in[5];
  float* out = (float*)d_out;

  char* p = (char*)d_ws;
  short* qkvb = (short*)p;                p += (size_t)kS * kQKVN * sizeof(short);  // 18.9 MB
  short* xb = (short*)p;                  p += (size_t)kS * kE * sizeof(short);     // 6.3 MB
  short* wb = (short*)p;                  p += (size_t)kQKVN * kE * sizeof(short);  // 3.5 MB
  short* owb = (short*)p;                 p += (size_t)kE * kE * sizeof(short);     // 1.2 MB
  short* attnb = (short*)p;               p += (size_t)kS * kE * sizeof(short);     // 6.3 MB
  float* clsp = (float*)p;                // 12*32*68 floats = 104 KB

  const int n4x = kS * kE / 4;
  const int n4w = kQKVN * kE / 4;
  const int n4o = kE * kE / 4;
  cvt3_kernel<<<2048, 256, 0, stream>>>(x, qkv_w, out_w, xb, wb, owb, n4x, n4w, n4o);

  // gemm1: 8-phase 256x256; 17 m-tiles x 9 n-tiles = 153 blocks, 512 threads
  gemm_8ph_kernel<true, short><<<153, 512, 0, stream>>>(xb, wb, qkv_b, qkvb, kS, kQKVN, kE, 17, coords);
  attn_kernel<<<768, 256, 0, stream>>>(qkvb, attnb, clsp);
  cls_combine_kernel<<<kH, 64, 0, stream>>>(clsp, attnb);
  // gemm2: r13 BK=64 kernel; 65 x 6 = 390 blocks
  gemm_tile_kernel<false, float><<<390, 256, 0, stream>>>(attnb, owb, out_b, out, kS, kE, kE, 65, nullptr);
}

// Round 17
// 95.594 us; speedup vs baseline: 1.1927x; 1.1927x over previous
//
#include <hip/hip_runtime.h>
#include <hip/hip_bf16.h>

namespace {

constexpr int kS = 4097;      // sequence incl. CLS
constexpr int kL = 4096;      // patch tokens
constexpr int kE = 768;
constexpr int kH = 12;
constexpr int kD = 64;
constexpr int kQKVN = 2304;
constexpr int kT = 1024;      // lattice length per residue (kL / kDil)
constexpr int kClsChunks = 32;
constexpr int kClsStride = 68;    // 64 acc + m + l, padded
constexpr float kScale = 0.125f;  // 1/sqrt(64)

typedef short short8 __attribute__((ext_vector_type(8)));
typedef short short4v __attribute__((ext_vector_type(4)));
typedef float f32x4 __attribute__((ext_vector_type(4)));

__device__ inline short f2bf(float x) {
  __hip_bfloat16 b = __float2bfloat16(x);
  return *reinterpret_cast<short*>(&b);
}
__device__ inline float bf2f(short u) {
  unsigned int x = ((unsigned int)(unsigned short)u) << 16;
  union { unsigned int u32; float f; } c;
  c.u32 = x;
  return c.f;
}

__device__ inline void store_c(float* p, float v) { *p = v; }
__device__ inline void store_c(short* p, float v) { *p = f2bf(v); }

// m204 bijective XCD swizzle: consecutive output ids share an XCD.
__device__ inline int xcd_swz(int bid, int nwg) {
  const int q = nwg >> 3, r = nwg & 7;
  const int x = bid & 7, o = bid >> 3;
  return (x < r ? x * (q + 1) : r * (q + 1) + (x - r) * q) + o;
}

#define GLOAD_LDS16(g, l)                                                        \
  __builtin_amdgcn_global_load_lds(                                              \
      (const __attribute__((address_space(1))) unsigned int*)(g),                \
      (__attribute__((address_space(3))) unsigned int*)(l), 16, 0, 0)

// Fused fp32->bf16 convert of x, qkv_w, out_w in one grid-stride kernel.
__global__ __launch_bounds__(256) void cvt3_kernel(const float* __restrict__ x,
                                                   const float* __restrict__ w,
                                                   const float* __restrict__ ow,
                                                   short* __restrict__ xb,
                                                   short* __restrict__ wb,
                                                   short* __restrict__ owb,
                                                   int n4x, int n4w, int n4o) {
  const int total = n4x + n4w + n4o;
  int i = blockIdx.x * blockDim.x + threadIdx.x;
  const int stride = gridDim.x * blockDim.x;
  for (; i < total; i += stride) {
    const float* src;
    short* dst;
    int k;
    if (i < n4x) { src = x; dst = xb; k = i; }
    else if (i < n4x + n4w) { src = w; dst = wb; k = i - n4x; }
    else { src = ow; dst = owb; k = i - n4x - n4w; }
    f32x4 v = reinterpret_cast<const f32x4*>(src)[k];
    short4v o;
#pragma unroll
    for (int j = 0; j < 4; ++j) o[j] = f2bf(v[j]);
    reinterpret_cast<short4v*>(dst)[k] = o;
  }
}

// 2-phase GEMM, 64x128 tile, BK=64 (12 barrier slots), chunk-XOR LDS swizzle
// (conflicts measured 0). C[M][N] = A*W^T + bias. 4 waves (2x2), per wave
// 2x4 frags x 2 k-substeps. global_load_lds writes linearly; the GLOBAL
// source 16B-chunk is pre-swizzled (chunk ^ (row&7), m173 pattern) and reads
// XOR the same -> 2-way banks (free). 48KB LDS -> 3 blocks/CU.
// 1D grid, m204 XCD swizzle. ROPE fused into the QKV-GEMM epilogue.
template <bool ROPE, typename TC>
__global__ __launch_bounds__(256) void gemm_tile_kernel(const short* __restrict__ A,
                                                        const short* __restrict__ W,
                                                        const float* __restrict__ bias,
                                                        TC* __restrict__ C,
                                                        int Mreal, int N, int K, int ntm,
                                                        const int* __restrict__ coords) {
  __shared__ short Ash[2][64 * 64];
  __shared__ short Bsh[2][128 * 64];
  const int nwg = gridDim.x;
  const int wid = xcd_swz(blockIdx.x, nwg);
  const int m0 = (wid % ntm) * 64;
  const int n0 = (wid / ntm) * 128;
  const int t = threadIdx.x;
  const int lane = t & 63;
  const int wave = t >> 6;
  const int wr = wave >> 1, wc = wave & 1;
  const int lrow = lane & 15;
  const int lgrp = lane >> 4;

  // Staging: thread t covers tile-row (t>>3) (+{0,32} A / +{0,32,64,96} B),
  // 16B chunk (t&7). Pre-swizzled source col: chunk ^ (tilerow&7); +32 rows
  // keep (row&7) -> one scol serves all passes. LDS dest linear = t*8.
  const int srow = t >> 3;   // 0..31
  const int scol = ((t & 7) ^ (srow & 7)) << 3;
  int ar0 = m0 + srow;       if (ar0 > Mreal - 1) ar0 = Mreal - 1;
  int ar1 = m0 + 32 + srow;  if (ar1 > Mreal - 1) ar1 = Mreal - 1;
  const int br0 = n0 + srow, br1 = n0 + 32 + srow;
  const int br2 = n0 + 64 + srow, br3 = n0 + 96 + srow;

#define STAGE(buf, k0)                                                  \
  do {                                                                  \
    GLOAD_LDS16(A + (size_t)ar0 * K + (k0) + scol, &Ash[buf][t * 8]);   \
    GLOAD_LDS16(A + (size_t)ar1 * K + (k0) + scol, &Ash[buf][2048 + t * 8]); \
    GLOAD_LDS16(W + (size_t)br0 * K + (k0) + scol, &Bsh[buf][t * 8]);   \
    GLOAD_LDS16(W + (size_t)br1 * K + (k0) + scol, &Bsh[buf][2048 + t * 8]); \
    GLOAD_LDS16(W + (size_t)br2 * K + (k0) + scol, &Bsh[buf][4096 + t * 8]); \
    GLOAD_LDS16(W + (size_t)br3 * K + (k0) + scol, &Bsh[buf][6144 + t * 8]); \
  } while (0)

  f32x4 acc[2][4] = {};
  const int nsteps = K / 64;  // 12

  STAGE(0, 0);
  __syncthreads();  // tile 0 resident

  int cur = 0;
  for (int tt = 0; tt < nsteps; ++tt) {
    if (tt + 1 < nsteps) STAGE(cur ^ 1, (tt + 1) * 64);  // prefetch overlaps MFMA

#pragma unroll
    for (int ks = 0; ks < 2; ++ks) {
      short8 a[2], b[4];
#pragma unroll
      for (int mi = 0; mi < 2; ++mi) {
        const int row = wr * 32 + mi * 16 + lrow;
        const int ch = (ks * 4 + lgrp) ^ (row & 7);
        a[mi] = *reinterpret_cast<const short8*>(&Ash[cur][row * 64 + ch * 8]);
      }
#pragma unroll
      for (int ni = 0; ni < 4; ++ni) {
        const int row = wc * 64 + ni * 16 + lrow;
        const int ch = (ks * 4 + lgrp) ^ (row & 7);
        b[ni] = *reinterpret_cast<const short8*>(&Bsh[cur][row * 64 + ch * 8]);
      }
#pragma unroll
      for (int mi = 0; mi < 2; ++mi)
#pragma unroll
        for (int ni = 0; ni < 4; ++ni)
          acc[mi][ni] = __builtin_amdgcn_mfma_f32_16x16x32_bf16(a[mi], b[ni], acc[mi][ni], 0, 0, 0);
    }

    __syncthreads();  // drains vmcnt+lgkm: next tile resident, reads done
    cur ^= 1;
  }
#undef STAGE

  // Epilogue. C/D layout (m89): col = lane&15, row = (lane>>4)*4 + reg.
  const int rg = lgrp << 2;
  for (int ni = 0; ni < 4; ++ni) {
    const int col = n0 + wc * 64 + ni * 16 + lrow;
    const float bz = bias[col];
    const int sec = col / 768;  // 0=q 1=k 2=v; uniform per ni (768%16==0)
    const int dh = col & 63;
    const bool odd = dh & 1;
    const int jf = (dh >> 1) & 15;
    const bool usex = (dh >> 1) < 16;
    const float invf = __powf(10000.0f, -(float)jf * (1.0f / 16.0f));
    for (int mi = 0; mi < 2; ++mi) {
      const int rowb = m0 + wr * 32 + mi * 16 + rg;
#pragma unroll
      for (int r = 0; r < 4; ++r) {
        const int row = rowb + r;
        float v = acc[mi][ni][r] + bz;
        if (ROPE && sec != 2) {
          const float partner = __shfl_xor(v, 1);  // pair element (w/ its bias)
          float cs = 1.f, sn = 0.f;
          if (row > 0) {  // uniform within 16-lane group
            const int cl = min(row, kS - 1) - 1;
            const float cx = (float)coords[cl * 2] * 1e-5f;
            const float cy = (float)coords[cl * 2 + 1] * 1e-5f;
            __sincosf((usex ? cx : cy) * invf, &sn, &cs);
          }
          v = odd ? (v * cs + partner * sn) : (v * cs - partner * sn);
          if (sec == 0) v *= kScale;  // q pre-scaled (incl CLS row)
        }
        if (row < Mreal) store_c(&C[(size_t)row * N + col], v);
      }
    }
  }
}

// Fused attention kernel:
//  blocks [0,384):   MFMA patch attention (lattice coords), 4 waves = 4 units
//  blocks [384,768): CLS split-K partials (h = idx>>5, chunk = idx&31)
__global__ __launch_bounds__(256) void attn_kernel(const short* __restrict__ qkv,
                                                   short* __restrict__ attn,
                                                   float* __restrict__ part) {
  __shared__ short Pl[4][32][104];
  __shared__ float sm[4], sl[4], sa[4][64];
  const int lane = threadIdx.x & 63;
  const int wv = threadIdx.x >> 6;

  if (blockIdx.x >= 384) {  // ---------- CLS partial ----------
    const int idx = blockIdx.x - 384;
    const int h = idx >> 5;
    const int c = idx & 31;
    const int start = c * 128;
    const int end = (c == kClsChunks - 1) ? kS : start + 128;
    const float qd = bf2f(qkv[h * kD + lane]);  // scaled q, row 0
    float m = -INFINITY, lsum = 0.f, acc = 0.f;
    for (int s = start + wv; s < end; s += 4) {
      float tt = qd * bf2f(qkv[(size_t)s * kQKVN + kE + h * kD + lane]);
      tt += __shfl_xor(tt, 1); tt += __shfl_xor(tt, 2); tt += __shfl_xor(tt, 4);
      tt += __shfl_xor(tt, 8); tt += __shfl_xor(tt, 16); tt += __shfl_xor(tt, 32);
      const float vd = bf2f(qkv[(size_t)s * kQKVN + 2 * kE + h * kD + lane]);
      const float mnew = fmaxf(m, tt);
      const float cor = __expf(m - mnew);
      const float p = __expf(tt - mnew);
      lsum = lsum * cor + p;
      acc = acc * cor + p * vd;
      m = mnew;
    }
    sa[wv][lane] = acc;
    if (lane == 0) { sm[wv] = m; sl[wv] = lsum; }
    __syncthreads();
    if (wv == 0) {
      float M = fmaxf(fmaxf(sm[0], sm[1]), fmaxf(sm[2], sm[3]));
      float Lt = 0.f, Av = 0.f;
#pragma unroll
      for (int w = 0; w < 4; ++w) {
        const float cw = __expf(sm[w] - M);
        Lt += sl[w] * cw;
        Av += sa[w][lane] * cw;
      }
      float* p = part + ((size_t)h * kClsChunks + c) * kClsStride;
      p[lane] = Av;
      if (lane == 0) { p[64] = M; p[65] = Lt; }
    }
    return;
  }

  // ---------- patch attention ----------
  const int unit = blockIdx.x * 4 + wv;
  const int t0 = (unit & 31) * 32;
  const int res = (unit >> 5) & 3;
  const int h = unit >> 7;
  const int lrow = lane & 15;
  const int lgrp = lane >> 4;
  const int kg = lgrp * 8;
  const int rg = lgrp * 4;

  // ---- QK^T ----
  f32x4 s_acc[2][4] = {};
  f32x4 s_cls[2] = {};
  short8 aq[2][2];
#pragma unroll
  for (int mi = 0; mi < 2; ++mi) {
    const int tq = t0 + mi * 16 + lrow;
    const size_t row = (size_t)(4 * tq + res + 1) * kQKVN + h * kD;
#pragma unroll
    for (int ks = 0; ks < 2; ++ks)
      aq[mi][ks] = *reinterpret_cast<const short8*>(qkv + row + ks * 32 + kg);
  }
#pragma unroll
  for (int ni = 0; ni < 4; ++ni) {
    int u = t0 - 16 + ni * 16 + lrow;
    u = min(max(u, 0), kT - 1);  // clamp; invalid cols masked in softmax
    const size_t row = (size_t)(4 * u + res + 1) * kQKVN + kE + h * kD;
    short8 bk[2];
#pragma unroll
    for (int ks = 0; ks < 2; ++ks)
      bk[ks] = *reinterpret_cast<const short8*>(qkv + row + ks * 32 + kg);
#pragma unroll
    for (int mi = 0; mi < 2; ++mi)
#pragma unroll
      for (int ks = 0; ks < 2; ++ks)
        s_acc[mi][ni] = __builtin_amdgcn_mfma_f32_16x16x32_bf16(aq[mi][ks], bk[ks], s_acc[mi][ni], 0, 0, 0);
  }
  {  // CLS key column
    short8 bc[2] = {};
    if (lrow == 0) {
#pragma unroll
      for (int ks = 0; ks < 2; ++ks)
        bc[ks] = *reinterpret_cast<const short8*>(qkv + kE + h * kD + ks * 32 + kg);
    }
#pragma unroll
    for (int mi = 0; mi < 2; ++mi)
#pragma unroll
      for (int ks = 0; ks < 2; ++ks)
        s_cls[mi] = __builtin_amdgcn_mfma_f32_16x16x32_bf16(aq[mi][ks], bc[ks], s_cls[mi], 0, 0, 0);
  }

  // ---- zero-fill P cols 64..95 ----
#pragma unroll
  for (int i = 0; i < 2; ++i) {
    const int idx = i * 64 + lane;
    const int q = idx >> 2, ch = idx & 3;
    short8 z = {};
    *reinterpret_cast<short8*>(&Pl[wv][q][64 + ch * 8]) = z;
  }

  // ---- softmax per query row (C-layout), write normalized P ----
#pragma unroll
  for (int mi = 0; mi < 2; ++mi) {
#pragma unroll
    for (int r = 0; r < 4; ++r) {
      const int q = mi * 16 + rg + r;
      float sw[4];
      float m = -INFINITY;
#pragma unroll
      for (int ni = 0; ni < 4; ++ni) {
        const int kk = ni * 16 + lrow;
        const int u = t0 - 16 + kk;
        const bool valid = (kk >= q) & (kk <= q + 32) & (u >= 0) & (u < kT);
        sw[ni] = valid ? s_acc[mi][ni][r] : -INFINITY;
        m = fmaxf(m, sw[ni]);
      }
      float scl = (lrow == 0) ? s_cls[mi][r] : -INFINITY;
      m = fmaxf(m, scl);
      m = fmaxf(m, __shfl_xor(m, 1)); m = fmaxf(m, __shfl_xor(m, 2));
      m = fmaxf(m, __shfl_xor(m, 4)); m = fmaxf(m, __shfl_xor(m, 8));
      float lsum = 0.f, ps[4];
#pragma unroll
      for (int ni = 0; ni < 4; ++ni) { ps[ni] = __expf(sw[ni] - m); lsum += ps[ni]; }
      const float pc = __expf(scl - m);
      lsum += pc;
      lsum += __shfl_xor(lsum, 1); lsum += __shfl_xor(lsum, 2);
      lsum += __shfl_xor(lsum, 4); lsum += __shfl_xor(lsum, 8);
      const float inv = __builtin_amdgcn_rcpf(lsum);
#pragma unroll
      for (int ni = 0; ni < 4; ++ni) Pl[wv][q][ni * 16 + lrow] = f2bf(ps[ni] * inv);
      if (lrow == 0) Pl[wv][q][64] = f2bf(pc * inv);
    }
  }

  // ---- PV: out[d][q] += V^T[d][kk] * P[q][kk] ----
  f32x4 o_acc[4][2] = {};
#pragma unroll
  for (int ks = 0; ks < 3; ++ks) {
    short8 bp[2];
#pragma unroll
    for (int nq = 0; nq < 2; ++nq)
      bp[nq] = *reinterpret_cast<const short8*>(&Pl[wv][nq * 16 + lrow][ks * 32 + kg]);
    short8 av[4];
#pragma unroll
    for (int md = 0; md < 4; ++md) {
      if (ks < 2) {
        const int d = md * 16 + lrow;
#pragma unroll
        for (int e = 0; e < 8; ++e) {
          const int kk = ks * 32 + kg + e;
          int u = t0 - 16 + kk;
          u = min(max(u, 0), kT - 1);  // invalid kk have P==0
          av[md][e] = qkv[(size_t)(4 * u + res + 1) * kQKVN + 2 * kE + h * kD + d];
        }
      } else {
        short8 z = {};
        av[md] = z;
        if (lgrp == 0)  // kk==64 -> v_cls
          av[md][0] = qkv[2 * kE + h * kD + md * 16 + lrow];
      }
#pragma unroll
      for (int nq = 0; nq < 2; ++nq)
        o_acc[md][nq] = __builtin_amdgcn_mfma_f32_16x16x32_bf16(av[md], bp[nq], o_acc[md][nq], 0, 0, 0);
    }
  }

  // ---- store ----
#pragma unroll
  for (int md = 0; md < 4; ++md)
#pragma unroll
    for (int nq = 0; nq < 2; ++nq)
#pragma unroll
      for (int r = 0; r < 4; ++r) {
        const int d = md * 16 + rg + r;
        const int q = nq * 16 + lrow;
        const int s = 4 * (t0 + q) + res + 1;
        attn[(size_t)s * kE + h * kD + d] = f2bf(o_acc[md][nq][r]);
      }
}

// CLS attention pass 2: combine 32 partials per head. 12 blocks x 64 lanes.
__global__ __launch_bounds__(64) void cls_combine_kernel(const float* __restrict__ part,
                                                         short* __restrict__ attn) {
  const int h = blockIdx.x;
  const int lane = threadIdx.x;
  float mc[kClsChunks], lc[kClsChunks], ac[kClsChunks];
#pragma unroll
  for (int c = 0; c < kClsChunks; ++c) {
    const float* p = part + ((size_t)h * kClsChunks + c) * kClsStride;
    mc[c] = p[64];
    lc[c] = p[65];
    ac[c] = p[lane];
  }
  float M = -INFINITY;
#pragma unroll
  for (int c = 0; c < kClsChunks; ++c) M = fmaxf(M, mc[c]);
  float L = 0.f, A = 0.f;
#pragma unroll
  for (int c = 0; c < kClsChunks; ++c) {
    const float w = __expf(mc[c] - M);
    L += lc[c] * w;
    A += ac[c] * w;
  }
  attn[h * kD + lane] = f2bf(A / L);
}

}  // namespace

extern "C" void kernel_launch(void* const* d_in, const int* in_sizes, int n_in,
                              void* d_out, int out_size, void* d_ws, size_t ws_size,
                              hipStream_t stream) {
  const float* x = (const float*)d_in[0];
  const int* coords = (const int*)d_in[1];
  const float* qkv_w = (const float*)d_in[2];
  const float* qkv_b = (const float*)d_in[3];
  const float* out_w = (const float*)d_in[4];
  const float* out_b = (const float*)d_in[5];
  float* out = (float*)d_out;

  char* p = (char*)d_ws;
  short* qkvb = (short*)p;                p += (size_t)kS * kQKVN * sizeof(short);  // 18.9 MB
  short* xb = (short*)p;                  p += (size_t)kS * kE * sizeof(short);     // 6.3 MB
  short* wb = (short*)p;                  p += (size_t)kQKVN * kE * sizeof(short);  // 3.5 MB
  short* owb = (short*)p;                 p += (size_t)kE * kE * sizeof(short);     // 1.2 MB
  short* attnb = (short*)p;               p += (size_t)kS * kE * sizeof(short);     // 6.3 MB
  float* clsp = (float*)p;                // 12*32*68 floats = 104 KB

  const int n4x = kS * kE / 4;
  const int n4w = kQKVN * kE / 4;
  const int n4o = kE * kE / 4;
  cvt3_kernel<<<2048, 256, 0, stream>>>(x, qkv_w, out_w, xb, wb, owb, n4x, n4w, n4o);

  // gemm1: 65 m-tiles x 18 n-tiles = 1170 blocks (1D, XCD-swizzled)
  gemm_tile_kernel<true, short><<<1170, 256, 0, stream>>>(xb, wb, qkv_b, qkvb, kS, kQKVN, kE, 65, coords);
  attn_kernel<<<768, 256, 0, stream>>>(qkvb, attnb, clsp);
  cls_combine_kernel<<<kH, 64, 0, stream>>>(clsp, attnb);
  // gemm2: 65 x 6 = 390 blocks
  gemm_tile_kernel<false, float><<<390, 256, 0, stream>>>(attnb, owb, out_b, out, kS, kE, kE, 65, nullptr);
}